// Round 2
// baseline (18037.343 us; speedup 1.0000x reference)
//
#include <hip/hip_runtime.h>

// Problem constants (hardcoded per reference)
constexpr int B = 32, L = 1024, D = 512, H = 512;

// LDS layout (floats). Rows padded: 8 slices x 68 (64 data + 4 pad) = 544.
constexpr int ROW = 544;
constexpr int HBUF_OFF = 0;       // 32*544 = 17408 floats
constexpr int WH_OFF   = 17408;   // 6*544  = 3264
constexpr int WX_OFF   = 20672;   // 6*544  = 3264
constexpr int BIAS_OFF = 23936;   // 8
constexpr int SMEM_FLOATS = 23944;
constexpr size_t SMEM_BYTES = SMEM_FLOATS * sizeof(float); // 95776 B < 160 KiB

// Workspace layout (dwords). h ping-pong + per-block flag lines + generation.
constexpr int NBLK = 256;
constexpr int FS = 32;                 // flag stride in dwords (128 B / line)
constexpr int HG0_OFF = 0;             // 16384 floats (h buffer, parity 0)
constexpr int HG1_OFF = 16384;         // 16384 floats (h buffer, parity 1)
constexpr int FLAGS_OFF = 32768;       // 256 * 32 dwords
constexpr int GEN_OFF = FLAGS_OFF + NBLK * FS;  // 40960
// total: 40961 dwords = 163844 bytes of d_ws used

__device__ __forceinline__ int padk(int k) { return 68 * (k >> 6) + (k & 63); }

__device__ __forceinline__ void st_flag(unsigned* p, unsigned v) {
    __hip_atomic_store(p, v, __ATOMIC_RELAXED, __HIP_MEMORY_SCOPE_AGENT);
}
__device__ __forceinline__ unsigned ld_flag(unsigned* p) {
    return __hip_atomic_load(p, __ATOMIC_RELAXED, __HIP_MEMORY_SCOPE_AGENT);
}

__global__ __launch_bounds__(256, 1)
void gru_persistent(const float* __restrict__ x, const float* __restrict__ h0,
                    const float* __restrict__ Wxz, const float* __restrict__ Whz,
                    const float* __restrict__ bz,
                    const float* __restrict__ Wxr, const float* __restrict__ Whr,
                    const float* __restrict__ br,
                    const float* __restrict__ Wxh, const float* __restrict__ Whh,
                    const float* __restrict__ bh,
                    float* __restrict__ out, unsigned* __restrict__ ws)
{
    extern __shared__ float smem[];
    float* hbuf = smem + HBUF_OFF;
    float* wh   = smem + WH_OFF;
    float* wx   = smem + WX_OFF;
    float* sb   = smem + BIAS_OFF;

    const int tid = threadIdx.x;
    const int bid = blockIdx.x;
    const int j0  = bid * 2;   // this wg owns features j0, j0+1

    float* hg0 = (float*)(ws + HG0_OFF);
    float* hg1 = (float*)(ws + HG1_OFF);
    unsigned* flags = ws + FLAGS_OFF;
    unsigned* gen   = ws + GEN_OFF;

    // ---- one-time staging: columns j0,j0+1 of all 6 weight matrices ----
    for (int g = 0; g < 3; ++g) {
        const float* Wh = (g == 0) ? Whz : (g == 1) ? Whr : Whh;
        const float* Wx = (g == 0) ? Wxz : (g == 1) ? Wxr : Wxh;
        for (int c = 0; c < 2; ++c) {
            const int k = tid + 256 * c;
            const int a = padk(k);
            for (int j = 0; j < 2; ++j) {
                wh[(2 * g + j) * ROW + a] = Wh[k * H + j0 + j];
                wx[(2 * g + j) * ROW + a] = Wx[k * H + j0 + j];
            }
        }
    }
    if (tid < 2) {
        sb[tid]     = bz[j0 + tid];
        sb[2 + tid] = br[j0 + tid];
        sb[4 + tid] = bh[j0 + tid];
    }
    // reset barrier state (d_ws is NOT re-poisoned between replays; stamps are
    // exact-matched so stale values from a prior call can never false-trigger,
    // but reset keeps the state space clean)
    if (tid == 0) {
        st_flag(&flags[bid * FS], 0u);
        if (bid == 0) st_flag(gen, 0u);
    }
    // init global h state (this wg's feature columns) into parity-0 buffer
    if (tid < 64) {
        const int bb = tid >> 1, j = tid & 1;
        __hip_atomic_store(&hg0[bb * H + j0 + j], h0[bb * H + j0 + j],
                           __ATOMIC_RELAXED, __HIP_MEMORY_SCOPE_AGENT);
    }
    asm volatile("s_waitcnt vmcnt(0)" ::: "memory");
    __syncthreads();
    if (tid == 0) st_flag(&flags[bid * FS], 1u);   // arrive at barrier stamp 1

    const int b = tid >> 3;          // batch row 0..31
    const int s = tid & 7;           // k-slice 0..7 (64 elems each)
    const float* xbase = x + (size_t)b * L * D + s * 64;
    const int wof = 68 * s;

    for (int t = 0; t < L; ++t) {
        // x slice for this step -> registers; issued BEFORE the barrier spin
        // so HBM latency hides under barrier wait
        float4 xv[16];
        const float4* xp = (const float4*)(xbase + (size_t)t * D);
#pragma unroll
        for (int c = 0; c < 16; ++c) xv[c] = xp[c];

        // ---- complete barrier stamp t+1 (guards reading h parity t&1) ----
        const unsigned stamp = (unsigned)(t + 1);
        if (bid == (t & 255)) {
            // rotating gatherer: 256 threads each poll one block's flag line
            while (ld_flag(&flags[tid * FS]) != stamp)
                __builtin_amdgcn_s_sleep(1);
            __syncthreads();
            if (tid == 0) st_flag(gen, stamp);
        } else {
            if (tid == 0) {
                while (ld_flag(gen) != stamp)
                    __builtin_amdgcn_s_sleep(1);
            }
            __syncthreads();
        }

        // ---- stage h parity (t&1) -> LDS via coherent 64-bit atomic loads ----
        const float* hsrc = (t & 1) ? hg1 : hg0;
        unsigned long long* hq = (unsigned long long*)hsrc;
#pragma unroll
        for (int c = 0; c < 32; ++c) {
            const int qi = c * 256 + tid;
            const unsigned long long v =
                __hip_atomic_load(&hq[qi], __ATOMIC_RELAXED, __HIP_MEMORY_SCOPE_AGENT);
            const int w = (qi * 2) & 511;
            float2 f;
            f.x = __uint_as_float((unsigned)v);
            f.y = __uint_as_float((unsigned)(v >> 32));
            *(float2*)(&hbuf[(qi >> 8) * ROW + padk(w)]) = f;
        }
        __syncthreads();

        float za[2] = {0.f, 0.f}, ra[2] = {0.f, 0.f};
        float xa[2] = {0.f, 0.f}, ha[2] = {0.f, 0.f};
        const float* hrow = hbuf + b * ROW + wof;
#pragma unroll
        for (int c = 0; c < 16; ++c) {
            const float4 h4 = *(const float4*)(hrow + 4 * c);
            const float4 x4 = xv[c];
#pragma unroll
            for (int j = 0; j < 2; ++j) {
                const float4 wz = *(const float4*)(wh + (0 + j) * ROW + wof + 4 * c);
                const float4 wr = *(const float4*)(wh + (2 + j) * ROW + wof + 4 * c);
                const float4 wc = *(const float4*)(wh + (4 + j) * ROW + wof + 4 * c);
                const float4 vz = *(const float4*)(wx + (0 + j) * ROW + wof + 4 * c);
                const float4 vr = *(const float4*)(wx + (2 + j) * ROW + wof + 4 * c);
                const float4 vc = *(const float4*)(wx + (4 + j) * ROW + wof + 4 * c);
                za[j] += h4.x*wz.x + h4.y*wz.y + h4.z*wz.z + h4.w*wz.w
                       + x4.x*vz.x + x4.y*vz.y + x4.z*vz.z + x4.w*vz.w;
                ra[j] += h4.x*wr.x + h4.y*wr.y + h4.z*wr.z + h4.w*wr.w
                       + x4.x*vr.x + x4.y*vr.y + x4.z*vr.z + x4.w*vr.w;
                ha[j] += h4.x*wc.x + h4.y*wc.y + h4.z*wc.z + h4.w*wc.w;
                xa[j] += x4.x*vc.x + x4.y*vc.y + x4.z*vc.z + x4.w*vc.w;
            }
        }
        // reduce partial dots across the 8 k-slices (low 3 bits of lane id)
#pragma unroll
        for (int m = 1; m < 8; m <<= 1) {
#pragma unroll
            for (int j = 0; j < 2; ++j) {
                za[j] += __shfl_xor(za[j], m);
                ra[j] += __shfl_xor(ra[j], m);
                xa[j] += __shfl_xor(xa[j], m);
                ha[j] += __shfl_xor(ha[j], m);
            }
        }
        if (s == 0) {
            float* hdst = ((t + 1) & 1) ? hg1 : hg0;
#pragma unroll
            for (int j = 0; j < 2; ++j) {
                const int f = j0 + j;
                const float z = 1.f / (1.f + __expf(-(za[j] + sb[j])));
                const float r = 1.f / (1.f + __expf(-(ra[j] + sb[2 + j])));
                const float pre = xa[j] + r * (ha[j] + sb[4 + j]);
                // tanh via exp, inf-safe
                const float e = __expf(-2.f * fabsf(pre));
                float th = (1.f - e) / (1.f + e);
                th = (pre < 0.f) ? -th : th;
                const float hold = hbuf[b * ROW + padk(f)];
                const float hn = z * hold + (1.f - z) * th;
                __hip_atomic_store(&hdst[b * H + f], hn,
                                   __ATOMIC_RELAXED, __HIP_MEMORY_SCOPE_AGENT);
                out[(size_t)(b * L + t) * H + f] = hn;
                if (t == L - 1) out[(size_t)B * L * H + b * H + f] = hn;
            }
        }
        // all of this block's h_new stores globally visible, then arrive
        asm volatile("s_waitcnt vmcnt(0)" ::: "memory");
        __syncthreads();
        if (t < L - 1 && tid == 0)
            st_flag(&flags[bid * FS], stamp + 1);   // arrive barrier t+2
    }
}

extern "C" void kernel_launch(void* const* d_in, const int* in_sizes, int n_in,
                              void* d_out, int out_size, void* d_ws, size_t ws_size,
                              hipStream_t stream) {
    const float* x   = (const float*)d_in[0];
    const float* h0  = (const float*)d_in[1];
    const float* Wxz = (const float*)d_in[2];
    const float* Whz = (const float*)d_in[3];
    const float* bz  = (const float*)d_in[4];
    const float* Wxr = (const float*)d_in[5];
    const float* Whr = (const float*)d_in[6];
    const float* br  = (const float*)d_in[7];
    const float* Wxh = (const float*)d_in[8];
    const float* Whh = (const float*)d_in[9];
    const float* bh  = (const float*)d_in[10];
    float* out = (float*)d_out;
    unsigned* ws = (unsigned*)d_ws;

    (void)hipFuncSetAttribute((const void*)gru_persistent,
                              hipFuncAttributeMaxDynamicSharedMemorySize,
                              (int)SMEM_BYTES);

    void* args[] = {(void*)&x, (void*)&h0, (void*)&Wxz, (void*)&Whz, (void*)&bz,
                    (void*)&Wxr, (void*)&Whr, (void*)&br, (void*)&Wxh, (void*)&Whh,
                    (void*)&bh, (void*)&out, (void*)&ws};
    (void)hipLaunchCooperativeKernel((void*)gru_persistent, dim3(256), dim3(256),
                                     args, (unsigned)SMEM_BYTES, stream);
}

// Round 4
// 7231.328 us; speedup vs baseline: 2.4943x; 2.4943x over previous
//
#include <hip/hip_runtime.h>
#include <hip/hip_bf16.h>

constexpr int B = 32, L = 1024, D = 512, H = 512;

// ---- LDS layout (dword offsets), all rows bank-swizzled ----
// WH: [3 gates][8 feats][512 k] f32      = 12288 dw (48 KiB)
// XW: [3 gates][8 feats][256 k-pairs] u32 (2×bf16) = 6144 dw (24 KiB)
// HB: [8 batch rows][512] f32 staged h   = 4096 dw (16 KiB)
// XB: [8 batch rows][512] f32 staged x   = 4096 dw (16 KiB)
constexpr int WH_OFF = 0;
constexpr int XW_OFF = 12288;
constexpr int HB_OFF = 18432;
constexpr int XB_OFF = 22528;
constexpr int LDS_DW = 26624;
constexpr size_t SMEM_BYTES = LDS_DW * 4ull;   // 106496 B (well under 160 KiB)

// ---- workspace layout (dword offsets) ----
constexpr int HGA_OFF = 0;          // h parity 0: [32][512] f32
constexpr int HGB_OFF = 16384;      // h parity 1
constexpr int FLAGS_OFF = 32768;    // [4 rings][64 members], stride 32 dw (128B)

using ull = unsigned long long;

__device__ __forceinline__ float dot4(float4 a, float4 b) {
    return a.x * b.x + a.y * b.y + a.z * b.z + a.w * b.w;
}
__device__ __forceinline__ float bflo(unsigned u) { return __uint_as_float(u << 16); }
__device__ __forceinline__ float bfhi(unsigned u) { return __uint_as_float(u & 0xffff0000u); }
__device__ __forceinline__ float bdot8(uint4 u, float4 lo, float4 hi) {
    return bflo(u.x)*lo.x + bfhi(u.x)*lo.y + bflo(u.y)*lo.z + bfhi(u.y)*lo.w
         + bflo(u.z)*hi.x + bfhi(u.z)*hi.y + bflo(u.w)*hi.z + bfhi(u.w)*hi.w;
}
// swizzled dword position of element k within a 512-dw row
__device__ __forceinline__ int swz(int k) {
    const int cg = k >> 2, e = k & 3, sup = cg >> 3;
    return sup * 32 + ((cg + sup) & 7) * 4 + e;
}
// same idea for a 256-dw row of k-pairs
__device__ __forceinline__ int swzp(int p) {
    const int cg = p >> 2, e = p & 3, sup = cg >> 3;
    return sup * 32 + ((cg + sup) & 7) * 4 + e;
}
// sum over lane bits 0..3 (VALU pipe: quad_perm xor1, xor2, row_ror:4, row_ror:8)
__device__ __forceinline__ float red16(float v) {
    int i;
    i = __builtin_amdgcn_update_dpp(0, __float_as_int(v), 0xB1, 0xf, 0xf, true);
    v += __int_as_float(i);
    i = __builtin_amdgcn_update_dpp(0, __float_as_int(v), 0x4E, 0xf, 0xf, true);
    v += __int_as_float(i);
    i = __builtin_amdgcn_update_dpp(0, __float_as_int(v), 0x124, 0xf, 0xf, true);
    v += __int_as_float(i);
    i = __builtin_amdgcn_update_dpp(0, __float_as_int(v), 0x128, 0xf, 0xf, true);
    v += __int_as_float(i);
    return v;
}
// full k-slice reduction: lane bits 0..3 via DPP, bit 5 via shfl_xor(32)
__device__ __forceinline__ float redk(float v) {
    v = red16(v);
    return v + __shfl_xor(v, 32);
}

__global__ __launch_bounds__(256, 1)
void gru_ring(const float* __restrict__ x, const float* __restrict__ h0,
              const float* __restrict__ Wxz, const float* __restrict__ Whz,
              const float* __restrict__ bz,
              const float* __restrict__ Wxr, const float* __restrict__ Whr,
              const float* __restrict__ br,
              const float* __restrict__ Wxh, const float* __restrict__ Whh,
              const float* __restrict__ bh,
              float* __restrict__ out, unsigned* __restrict__ ws)
{
    extern __shared__ float lds[];
    float*    WHl = lds + WH_OFF;
    unsigned* XWl = (unsigned*)(lds + XW_OFF);
    float*    HBl = lds + HB_OFF;
    float*    XBl = lds + XB_OFF;

    const int tid = threadIdx.x;
    const int bid = blockIdx.x;
    const int g   = bid >> 6;        // ring 0..3: batches g*8 .. g*8+7
    const int fc  = bid & 63;        // member: features F0 .. F0+7
    const int F0  = fc * 8;

    float*    hgA   = (float*)(ws + HGA_OFF);
    float*    hgB   = (float*)(ws + HGB_OFF);
    unsigned* flags = ws + FLAGS_OFF + g * 64 * 32;   // ring-local

    // ---------------- one-time weight staging ----------------
    for (int gi = 0; gi < 3; ++gi) {
        const float* Wh = gi == 0 ? Whz : gi == 1 ? Whr : Whh;
        const float* Wx = gi == 0 ? Wxz : gi == 1 ? Wxr : Wxh;
        for (int rep = 0; rep < 2; ++rep) {
            const int k = tid + rep * 256;
            const float* src = Wh + (size_t)k * H + F0;
            const float4 a = *(const float4*)(src);
            const float4 b = *(const float4*)(src + 4);
            const float va[8] = {a.x, a.y, a.z, a.w, b.x, b.y, b.z, b.w};
            const int dk = swz(k);
#pragma unroll
            for (int f = 0; f < 8; ++f)
                WHl[(gi * 8 + f) * 512 + dk] = va[f];
        }
        {
            const int p = tid;               // k-pair: rows 2p, 2p+1
            const float* s0 = Wx + (size_t)(2 * p) * H + F0;
            const float* s1 = Wx + (size_t)(2 * p + 1) * H + F0;
            const float4 a0 = *(const float4*)(s0), b0 = *(const float4*)(s0 + 4);
            const float4 a1 = *(const float4*)(s1), b1 = *(const float4*)(s1 + 4);
            const float v0[8] = {a0.x, a0.y, a0.z, a0.w, b0.x, b0.y, b0.z, b0.w};
            const float v1[8] = {a1.x, a1.y, a1.z, a1.w, b1.x, b1.y, b1.z, b1.w};
            const int dp = swzp(p);
#pragma unroll
            for (int f = 0; f < 8; ++f) {
                __hip_bfloat16 lo = __float2bfloat16(v0[f]);
                __hip_bfloat16 hi = __float2bfloat16(v1[f]);
                const unsigned u = ((unsigned)*(unsigned short*)&hi << 16) |
                                   (unsigned)*(unsigned short*)&lo;
                XWl[(gi * 8 + f) * 256 + dp] = u;
            }
        }
    }

    // ---- compute-role decomposition ----
    // lane bits: 0..3 = ks_low, 4 = bh (batch half), 5 = ks_hi; bits 6..7 = f2
    const int ks = (tid & 15) | ((tid & 32) >> 1);   // k-slice 0..31 (16 k each)
    const int bhalf = (tid >> 4) & 1;                // batches bhalf*4 .. +3
    const int f2 = tid >> 6;                         // feature pair 2f2, 2f2+1

    int oh[4];
    {
        const int sup = ks >> 1;
#pragma unroll
        for (int c = 0; c < 4; ++c)
            oh[c] = sup * 32 + (((4 * ks + c) + sup) & 7) * 4;
    }
    int ox2[2];
    {
        const int sup = ks >> 2;
#pragma unroll
        for (int cc = 0; cc < 2; ++cc)
            ox2[cc] = sup * 32 + (((2 * ks + cc) + sup) & 7) * 4;
    }

    // biases for this thread's 2 features
    const int f0g = F0 + 2 * f2;
    const float bz0 = bz[f0g], bz1 = bz[f0g + 1];
    const float br0 = br[f0g], br1 = br[f0g + 1];
    const float bhv0 = bh[f0g], bhv1 = bh[f0g + 1];

    // ---- staging roles: row rr (ring-local batch), 16 cols from cbase ----
    const int rr    = tid >> 5;
    const int cbase = (tid & 31) * 16;
    int os[4];
    {
        const int kss = tid & 31, sup = kss >> 1;
#pragma unroll
        for (int c = 0; c < 4; ++c)
            os[c] = sup * 32 + (((4 * kss + c) + sup) & 7) * 4;
    }

    // init h parity-0 with this block's own feature columns
    if (tid < 64) {
        const int bb = tid >> 3, j = tid & 7;
        const int idx = (g * 8 + bb) * H + F0 + j;
        __hip_atomic_store(&hgA[idx], h0[idx], __ATOMIC_RELAXED,
                           __HIP_MEMORY_SCOPE_AGENT);
    }

    // prefetch x for t=0
    float4 xr[4];
    {
        const float* xp = x + ((size_t)(g * 8 + rr) * L + 0) * D + cbase;
#pragma unroll
        for (int c = 0; c < 4; ++c) xr[c] = *(const float4*)(xp + 4 * c);
    }

    asm volatile("s_waitcnt vmcnt(0)" ::: "memory");
    __syncthreads();
    if (tid == 0)
        __hip_atomic_store(&flags[fc * 32], 1u, __ATOMIC_RELAXED,
                           __HIP_MEMORY_SCOPE_AGENT);

    for (int t = 0; t < L; ++t) {
        // ---- ring barrier: all 64 members' flags in {t+1, t+2} ----
        const unsigned stamp = (unsigned)(t + 1);
        if (tid < 64) {
            unsigned v;
            do {
                v = __hip_atomic_load(&flags[tid * 32], __ATOMIC_RELAXED,
                                      __HIP_MEMORY_SCOPE_AGENT);
                if (__all((v - stamp) <= 1u)) break;
                __builtin_amdgcn_s_sleep(1);
            } while (true);
        }
        __syncthreads();

        // ---- stage h (coherent loads) + x (prefetched regs) into LDS ----
        {
            const float* hsrc = ((t & 1) ? hgB : hgA) + (g * 8 + rr) * 512 + cbase;
            const ull* hq = (const ull*)hsrc;
#pragma unroll
            for (int c = 0; c < 4; ++c) {
                const ull q0 = __hip_atomic_load(hq + 2 * c,     __ATOMIC_RELAXED, __HIP_MEMORY_SCOPE_AGENT);
                const ull q1 = __hip_atomic_load(hq + 2 * c + 1, __ATOMIC_RELAXED, __HIP_MEMORY_SCOPE_AGENT);
                float4 h4;
                h4.x = __uint_as_float((unsigned)q0);
                h4.y = __uint_as_float((unsigned)(q0 >> 32));
                h4.z = __uint_as_float((unsigned)q1);
                h4.w = __uint_as_float((unsigned)(q1 >> 32));
                *(float4*)(HBl + rr * 512 + os[c]) = h4;
                *(float4*)(XBl + rr * 512 + os[c]) = xr[c];
            }
        }
        __syncthreads();

        // ---- prefetch x for t+1 (latency hides under compute) ----
        if (t + 1 < L) {
            const float* xp = x + ((size_t)(g * 8 + rr) * L + (t + 1)) * D + cbase;
#pragma unroll
            for (int c = 0; c < 4; ++c) xr[c] = *(const float4*)(xp + 4 * c);
        }

        // ---- compute: 4 batches × 2 feats × 3 gates over this 16-k slice ----
        float az[4][2] = {}, ar[4][2] = {}, ac[4][2] = {}, ax[4][2] = {};
        {
            const float* W0 = WHl + (0 * 8 + 2 * f2) * 512;
            const float* W1 = WHl + (1 * 8 + 2 * f2) * 512;
            const float* W2 = WHl + (2 * 8 + 2 * f2) * 512;
            const float* hb = HBl + (bhalf * 4) * 512;
#pragma unroll
            for (int c = 0; c < 4; ++c) {
                const int o = oh[c];
                const float4 wz0 = *(const float4*)(W0 + o);
                const float4 wz1 = *(const float4*)(W0 + 512 + o);
                const float4 wr0 = *(const float4*)(W1 + o);
                const float4 wr1 = *(const float4*)(W1 + 512 + o);
                const float4 wc0 = *(const float4*)(W2 + o);
                const float4 wc1 = *(const float4*)(W2 + 512 + o);
#pragma unroll
                for (int b = 0; b < 4; ++b) {
                    const float4 h4 = *(const float4*)(hb + b * 512 + o);
                    az[b][0] += dot4(h4, wz0); az[b][1] += dot4(h4, wz1);
                    ar[b][0] += dot4(h4, wr0); ar[b][1] += dot4(h4, wr1);
                    ac[b][0] += dot4(h4, wc0); ac[b][1] += dot4(h4, wc1);
                }
            }
            const unsigned* U0 = XWl + (0 * 8 + 2 * f2) * 256;
            const unsigned* U1 = XWl + (1 * 8 + 2 * f2) * 256;
            const unsigned* U2 = XWl + (2 * 8 + 2 * f2) * 256;
            const float* xb = XBl + (bhalf * 4) * 512;
#pragma unroll
            for (int cc = 0; cc < 2; ++cc) {
                const int o2 = ox2[cc];
                const uint4 uz0 = *(const uint4*)(U0 + o2);
                const uint4 uz1 = *(const uint4*)(U0 + 256 + o2);
                const uint4 ur0 = *(const uint4*)(U1 + o2);
                const uint4 ur1 = *(const uint4*)(U1 + 256 + o2);
                const uint4 uc0 = *(const uint4*)(U2 + o2);
                const uint4 uc1 = *(const uint4*)(U2 + 256 + o2);
#pragma unroll
                for (int b = 0; b < 4; ++b) {
                    const float4 xlo = *(const float4*)(xb + b * 512 + oh[2 * cc]);
                    const float4 xhi = *(const float4*)(xb + b * 512 + oh[2 * cc + 1]);
                    az[b][0] += bdot8(uz0, xlo, xhi); az[b][1] += bdot8(uz1, xlo, xhi);
                    ar[b][0] += bdot8(ur0, xlo, xhi); ar[b][1] += bdot8(ur1, xlo, xhi);
                    ax[b][0] += bdot8(uc0, xlo, xhi); ax[b][1] += bdot8(uc1, xlo, xhi);
                }
            }
        }

        // ---- reduce over the 32 k-slices (lane bits 0..3 and 5) ----
#pragma unroll
        for (int b = 0; b < 4; ++b) {
#pragma unroll
            for (int j = 0; j < 2; ++j) {
                az[b][j] = redk(az[b][j]);
                ar[b][j] = redk(ar[b][j]);
                ac[b][j] = redk(ac[b][j]);
                ax[b][j] = redk(ax[b][j]);
            }
        }

        // ---- epilogue: ks==0 threads finalize 4 batches × 2 features ----
        float2 outv[4];
        const bool epi = (tid & 0x2F) == 0;
        if (epi) {
            float* hdst = ((t + 1) & 1) ? hgB : hgA;
            const int offh = swz(f0g);
#pragma unroll
            for (int b = 0; b < 4; ++b) {
                const int bb = bhalf * 4 + b;
                const int bg = g * 8 + bb;
                const float hold0 = HBl[bb * 512 + offh];
                const float hold1 = HBl[bb * 512 + offh + 1];

                const float z0 = 1.f / (1.f + __expf(-(az[b][0] + bz0)));
                const float r0 = 1.f / (1.f + __expf(-(ar[b][0] + br0)));
                const float p0 = ax[b][0] + r0 * (ac[b][0] + bhv0);
                const float e0 = __expf(-2.f * fabsf(p0));
                float th0 = (1.f - e0) / (1.f + e0);
                th0 = (p0 < 0.f) ? -th0 : th0;
                const float hn0 = z0 * hold0 + (1.f - z0) * th0;

                const float z1 = 1.f / (1.f + __expf(-(az[b][1] + bz1)));
                const float r1 = 1.f / (1.f + __expf(-(ar[b][1] + br1)));
                const float p1 = ax[b][1] + r1 * (ac[b][1] + bhv1);
                const float e1 = __expf(-2.f * fabsf(p1));
                float th1 = (1.f - e1) / (1.f + e1);
                th1 = (p1 < 0.f) ? -th1 : th1;
                const float hn1 = z1 * hold1 + (1.f - z1) * th1;

                const ull hp = ((ull)__float_as_uint(hn1) << 32) | __float_as_uint(hn0);
                __hip_atomic_store((ull*)(hdst + bg * 512 + f0g), hp,
                                   __ATOMIC_RELAXED, __HIP_MEMORY_SCOPE_AGENT);
                outv[b] = make_float2(hn0, hn1);
            }
        }

        // h stores globally acked, then arrive
        asm volatile("s_waitcnt vmcnt(0)" ::: "memory");
        __syncthreads();
        if (tid == 0)
            __hip_atomic_store(&flags[fc * 32], stamp + 1u, __ATOMIC_RELAXED,
                               __HIP_MEMORY_SCOPE_AGENT);

        // out writes off the critical path
        if (epi) {
#pragma unroll
            for (int b = 0; b < 4; ++b) {
                const int bg = g * 8 + bhalf * 4 + b;
                *(float2*)(out + ((size_t)bg * L + t) * H + f0g) = outv[b];
                if (t == L - 1)
                    *(float2*)(out + (size_t)B * L * H + (size_t)bg * H + f0g) = outv[b];
            }
        }
    }
}

extern "C" void kernel_launch(void* const* d_in, const int* in_sizes, int n_in,
                              void* d_out, int out_size, void* d_ws, size_t ws_size,
                              hipStream_t stream) {
    const float* x   = (const float*)d_in[0];
    const float* h0  = (const float*)d_in[1];
    const float* Wxz = (const float*)d_in[2];
    const float* Whz = (const float*)d_in[3];
    const float* bz  = (const float*)d_in[4];
    const float* Wxr = (const float*)d_in[5];
    const float* Whr = (const float*)d_in[6];
    const float* br  = (const float*)d_in[7];
    const float* Wxh = (const float*)d_in[8];
    const float* Whh = (const float*)d_in[9];
    const float* bh  = (const float*)d_in[10];
    float* out = (float*)d_out;
    unsigned* ws = (unsigned*)d_ws;

    (void)hipFuncSetAttribute((const void*)gru_ring,
                              hipFuncAttributeMaxDynamicSharedMemorySize,
                              (int)SMEM_BYTES);

    void* args[] = {(void*)&x, (void*)&h0, (void*)&Wxz, (void*)&Whz, (void*)&bz,
                    (void*)&Wxr, (void*)&Whr, (void*)&br, (void*)&Wxh, (void*)&Whh,
                    (void*)&bh, (void*)&out, (void*)&ws};
    hipError_t err = hipLaunchCooperativeKernel((void*)gru_ring, dim3(256),
                                                dim3(256), args,
                                                (unsigned)SMEM_BYTES, stream);
    if (err != hipSuccess) {
        // kernel uses only its own flag barrier; 256 blocks at 1/CU are
        // trivially co-resident, so a plain launch is a safe fallback
        gru_ring<<<dim3(256), dim3(256), SMEM_BYTES, stream>>>(
            x, h0, Wxz, Whz, bz, Wxr, Whr, br, Wxh, Whh, bh, out, ws);
    }
}